// Round 11
// baseline (3936.108 us; speedup 1.0000x reference)
//
#include <hip/hip_runtime.h>

typedef _Float16 h8 __attribute__((ext_vector_type(8)));
typedef float v4f __attribute__((ext_vector_type(4)));
typedef unsigned long long u64;

#define B_  256
#define T_  512
#define I_  64
#define H_  512

// workspace layout (bytes)
#define OFF_W16   0                                   // [2048][512] f16
#define OFF_WIH   (OFF_W16 + 2048*512*2)              // [2048][64]  f16
#define OFF_BIAS  (OFF_WIH + 2048*64*2)               // [2048]      f32 (b_ih+b_hh)
#define OFF_X16   (OFF_BIAS + 2048*4)                 // [512][256][64] f16 (t-major)
#define OFF_H0    (OFF_X16 + 512*256*64*2)            // [256][512] f16
#define OFF_H1    (OFF_H0 + 256*512*2)                // [256][512] f16
#define OFF_CTR   (OFF_H1 + 256*512*2)                // 16 counters, 64B apart

// LDS chunk stride 1040 = 1024+16 (r6/r9-verified: writes 4 dwords/bank, reads 8/bank)
#define CS_ 1040

__device__ __forceinline__ float sigf(float x) {
    float e = __builtin_amdgcn_exp2f(-1.442695041f * x);
    return __builtin_amdgcn_rcpf(1.f + e);
}
__device__ __forceinline__ float tanhf_(float x) {
    float e = __builtin_amdgcn_exp2f(2.885390082f * x);  // exp(2x)
    return 1.f - 2.f * __builtin_amdgcn_rcpf(e + 1.f);
}

union Pack4 { _Float16 f[4]; u64 u; };

__global__ void prep_w(const float* __restrict__ Wih, const float* __restrict__ Whh,
                       const float* __restrict__ bih, const float* __restrict__ bhh,
                       _Float16* __restrict__ W16, _Float16* __restrict__ Wih16,
                       float* __restrict__ bias, _Float16* __restrict__ h0,
                       unsigned* __restrict__ ctr) {
    int idx = blockIdx.x * 256 + threadIdx.x;          // grid covers 2048*512
    W16[idx] = (_Float16)Whh[idx];
    if (idx < 2048 * 64)  Wih16[idx] = (_Float16)Wih[idx];
    if (idx < 2048)       bias[idx] = bih[idx] + bhh[idx];
    // h0 zeros must be visible at the IF$ coherence point (lstm_k reads them
    // with device-scope loads that bypass L2) -> device-scope atomic stores.
    if (idx < 32768)
        __hip_atomic_store((u64*)h0 + idx, 0ull,
                           __ATOMIC_RELAXED, __HIP_MEMORY_SCOPE_AGENT);
    if (idx < 256)
        __hip_atomic_store(ctr + idx, 0u, __ATOMIC_RELAXED, __HIP_MEMORY_SCOPE_AGENT);
}

__global__ void prep_x(const float* __restrict__ x, _Float16* __restrict__ x16) {
    int idx = blockIdx.x * 256 + threadIdx.x;          // grid covers 512*256*64
    int t = idx >> 14;                                  // / (256*64)
    int rem = idx & 16383;
    int b = rem >> 6;
    int i = rem & 63;
    x16[idx] = (_Float16)x[((size_t)b * T_ + t) * I_ + i];
}

// r9 (1306us steady, champion) widened along h-cols to shrink the rendezvous:
// 64 wgs = 16 bg x 4 cg; wg = 16 batch rows x 128 h-cols, 8 waves (512 thr).
// Per-wave work UNCHANGED (16 cols x 4 gates, same afrag/K-loop); total waves
// unchanged (1024). Deltas vs r9:
//   - producers per bg: 8 -> 4 (shorter RMW chain, skew tail max-of-4)
//   - staging per thread halves (4 u64; same 16KB tile shared by 8 waves)
//   - blockIdx = bg + 16*cg -> the 4 producers of a bg share blockIdx%8
// Protocol byte-identical to r9 (RMW + tid0 poll + last-publisher skip;
// r4/r7/r8 proved every other protocol variant regresses). Bank balance
// re-verified at 512 threads: writes 4 dwords/bank, b128 reads 8/bank.
__launch_bounds__(512, 1)
__global__ void lstm_k(const _Float16* __restrict__ W16, const _Float16* __restrict__ Wih16,
                       const float* __restrict__ bias, const _Float16* __restrict__ x16,
                       _Float16* __restrict__ h0, _Float16* __restrict__ h1,
                       unsigned* __restrict__ ctr) {
    __shared__ __align__(16) char Ab[16 * CS_];   // 16640 B, h-tile staging

    const int tid  = threadIdx.x;
    const int lane = tid & 63;
    const int wv   = tid >> 6;        // wave = h-col sub-block (0..7)
    const int bg   = blockIdx.x & 15; // batch group (16 rows)
    const int cg   = blockIdx.x >> 4; // column group 0..3
    const int B0   = bg * 16;
    const int J0   = cg * 128;        // h-column base (128 cols per wg)
    const int r    = lane & 15;
    const int q    = lane >> 4;

    // --- hoist weights as A-frags: 4 gates x 16 h-chunks + 2 x-chunks ---
    h8 afrag[4][16];
    h8 xafrag[4][2];
    float biasv[4][4];
#pragma unroll
    for (int g = 0; g < 4; ++g) {
        const int wrow = g * H_ + J0 + wv * 16 + r;     // gate-col index (A row)
#pragma unroll
        for (int kk = 0; kk < 16; ++kk)
            afrag[g][kk] = *(const h8*)(W16 + (size_t)wrow * H_ + kk * 32 + q * 8);
#pragma unroll
        for (int c = 0; c < 2; ++c)
            xafrag[g][c] = *(const h8*)(Wih16 + (size_t)wrow * I_ + c * 32 + q * 8);
        // D rows (M=gate-col) = q*4+reg -> bias per (g, reg)
#pragma unroll
        for (int reg = 0; reg < 4; ++reg)
            biasv[g][reg] = bias[g * H_ + J0 + wv * 16 + q * 4 + reg];
    }

    // staging constants: unit u = tid + 512*it -> row = (tid>>7)+4*it,
    // kk = (tid>>3)&15, byte = kk*CS_ + row*64 + (tid&7)*8
    const int wbase = ((tid >> 3) & 15) * CS_ + (tid & 7) * 8;
    const int rw0   = tid >> 7;       // 0..3
    // B-frag (h) read base: chunk kk, batch row r, bytes q*16..
    const int rb0 = r * 64 + q * 16;

    // cell state: lane owns batch row B0+r, h-cols J0+wv*16+q*4+{0..3}
    float cc[4] = {0.f, 0.f, 0.f, 0.f};

    unsigned* myctr = ctr + bg * 16;  // 64B-separated per-bg counters

    // x B-frags for step 0: lane (r,q) needs x16[t][B0+r][c*32 + q*8 ..+7]
    const _Float16* xrow0 = x16 + (size_t)(B0 + r) * I_ + q * 8;
    h8 xa0 = *(const h8*)(xrow0);
    h8 xa1 = *(const h8*)(xrow0 + 32);

    for (int s = 0; s < T_; ++s) {
        const _Float16* hp = (s & 1) ? h1 : h0;
        _Float16*       hn = (s & 1) ? h0 : h1;

        // ---- phase A: issue h agent-loads (bypass L1/L2), coalesced ----
        u64 hv[4];
        {
            const u64* hp64 = (const u64*)(hp + (size_t)B0 * H_);
#pragma unroll
            for (int it = 0; it < 4; ++it)
                hv[it] = __hip_atomic_load(hp64 + tid + 512 * it,
                                           __ATOMIC_RELAXED, __HIP_MEMORY_SCOPE_AGENT);
        }

        // ---- x-part MFMAs overlap the h-load latency (register-only) ----
        v4f a0 = {0,0,0,0}, a1 = {0,0,0,0}, a2 = {0,0,0,0}, a3 = {0,0,0,0};
        a0 = __builtin_amdgcn_mfma_f32_16x16x32_f16(xafrag[0][0], xa0, a0, 0, 0, 0);
        a1 = __builtin_amdgcn_mfma_f32_16x16x32_f16(xafrag[1][0], xa0, a1, 0, 0, 0);
        a2 = __builtin_amdgcn_mfma_f32_16x16x32_f16(xafrag[2][0], xa0, a2, 0, 0, 0);
        a3 = __builtin_amdgcn_mfma_f32_16x16x32_f16(xafrag[3][0], xa0, a3, 0, 0, 0);
        a0 = __builtin_amdgcn_mfma_f32_16x16x32_f16(xafrag[0][1], xa1, a0, 0, 0, 0);
        a1 = __builtin_amdgcn_mfma_f32_16x16x32_f16(xafrag[1][1], xa1, a1, 0, 0, 0);
        a2 = __builtin_amdgcn_mfma_f32_16x16x32_f16(xafrag[2][1], xa1, a2, 0, 0, 0);
        a3 = __builtin_amdgcn_mfma_f32_16x16x32_f16(xafrag[3][1], xa1, a3, 0, 0, 0);

        // ---- stage h into LDS (waits loads), barrier ----
#pragma unroll
        for (int it = 0; it < 4; ++it) {
            int row = rw0 + 4 * it;
            *(u64*)(Ab + wbase + row * 64) = hv[it];
        }
        __syncthreads();

        // ---- phase B: h-part MFMA, 16 chunks; B-frag (h) feeds 4 gates ----
#pragma unroll
        for (int kk = 0; kk < 16; ++kk) {
            const h8 bm = *(const h8*)(Ab + kk * CS_ + rb0);
            a0 = __builtin_amdgcn_mfma_f32_16x16x32_f16(afrag[0][kk], bm, a0, 0, 0, 0);
            a1 = __builtin_amdgcn_mfma_f32_16x16x32_f16(afrag[1][kk], bm, a1, 0, 0, 0);
            a2 = __builtin_amdgcn_mfma_f32_16x16x32_f16(afrag[2][kk], bm, a2, 0, 0, 0);
            a3 = __builtin_amdgcn_mfma_f32_16x16x32_f16(afrag[3][kk], bm, a3, 0, 0, 0);
        }

        // ---- phase C: cell in registers; ONE packed 8B h' store per lane ----
        // C/D [m89]: col = lane&15 = batch r; row = q*4+reg = h-col offset
        {
            Pack4 pk;
#pragma unroll
            for (int reg = 0; reg < 4; ++reg) {
                float iv = sigf  (a0[reg] + biasv[0][reg]);
                float fv = sigf  (a1[reg] + biasv[1][reg]);
                float gv = tanhf_(a2[reg] + biasv[2][reg]);
                float ov = sigf  (a3[reg] + biasv[3][reg]);
                cc[reg] = fv * cc[reg] + iv * gv;
                pk.f[reg] = (_Float16)(ov * tanhf_(cc[reg]));
            }
            __hip_atomic_store(
                (u64*)(hn + (size_t)(B0 + r) * H_ + J0 + wv * 16 + q * 4),
                pk.u, __ATOMIC_RELAXED, __HIP_MEMORY_SCOPE_AGENT);
        }
        __syncthreads();   // implicit vmcnt(0): all waves' h' stores ack'd at IF$

        // ---- per-group barrier: counter RMW; last publisher skips the poll ----
        unsigned old = 0;
        const unsigned target = 4u * (unsigned)(s + 1);
        if (tid == 0)
            old = __hip_atomic_fetch_add(myctr, 1u,
                                         __ATOMIC_RELAXED, __HIP_MEMORY_SCOPE_AGENT);
        // x B-frag prefetch for s+1 overlaps the RMW/poll
        if (s + 1 < T_) {
            const _Float16* xr = x16 + ((size_t)(s + 1) * B_ + B0 + r) * I_ + q * 8;
            xa0 = *(const h8*)(xr);
            xa1 = *(const h8*)(xr + 32);
        }
        if (tid == 0 && old + 1 < target) {
            int guard = 0;
            while (__hip_atomic_load(myctr, __ATOMIC_RELAXED, __HIP_MEMORY_SCOPE_AGENT) < target) {
                __builtin_amdgcn_s_sleep(1);
                if (++guard > (1 << 17)) break;   // anti-hang: fail loud, not silent
            }
        }
        __syncthreads();
    }
}

__global__ void fc_k(const _Float16* __restrict__ hlast, const float* __restrict__ Wfc,
                     const float* __restrict__ bfc, float* __restrict__ out) {
    int b = blockIdx.x;
    int lane = threadIdx.x;   // 64 threads
    // h was written with device-scope stores (bypassing L2) -> read device-scope
    const u64* hp64 = (const u64*)(hlast + (size_t)b * H_);
    Pack4 p0, p1;
    p0.u = __hip_atomic_load(hp64 + lane * 2,     __ATOMIC_RELAXED, __HIP_MEMORY_SCOPE_AGENT);
    p1.u = __hip_atomic_load(hp64 + lane * 2 + 1, __ATOMIC_RELAXED, __HIP_MEMORY_SCOPE_AGENT);
    float sum = 0.f;
#pragma unroll
    for (int j = 0; j < 4; ++j) sum += (float)p0.f[j] * Wfc[lane * 8 + j];
#pragma unroll
    for (int j = 0; j < 4; ++j) sum += (float)p1.f[j] * Wfc[lane * 8 + 4 + j];
    for (int off = 32; off; off >>= 1) sum += __shfl_down(sum, off);
    if (lane == 0) out[b] = sum + bfc[0];
}

extern "C" void kernel_launch(void* const* d_in, const int* in_sizes, int n_in,
                              void* d_out, int out_size, void* d_ws, size_t ws_size,
                              hipStream_t stream) {
    (void)in_sizes; (void)n_in; (void)out_size; (void)ws_size;
    const float* x   = (const float*)d_in[0];
    const float* Wih = (const float*)d_in[1];
    const float* Whh = (const float*)d_in[2];
    const float* bih = (const float*)d_in[3];
    const float* bhh = (const float*)d_in[4];
    const float* Wfc = (const float*)d_in[5];
    const float* bfc = (const float*)d_in[6];
    float* out = (float*)d_out;

    char* ws = (char*)d_ws;
    _Float16* W16   = (_Float16*)(ws + OFF_W16);
    _Float16* Wih16 = (_Float16*)(ws + OFF_WIH);
    float*    biasf = (float*)(ws + OFF_BIAS);
    _Float16* x16   = (_Float16*)(ws + OFF_X16);
    _Float16* h0b   = (_Float16*)(ws + OFF_H0);
    _Float16* h1b   = (_Float16*)(ws + OFF_H1);
    unsigned* ctrb  = (unsigned*)(ws + OFF_CTR);

    hipLaunchKernelGGL(prep_w, dim3((2048 * 512) / 256), dim3(256), 0, stream,
                       Wih, Whh, bih, bhh, W16, Wih16, biasf, h0b, ctrb);
    hipLaunchKernelGGL(prep_x, dim3((512 * 256 * 64) / 256), dim3(256), 0, stream, x, x16);
    hipLaunchKernelGGL(lstm_k, dim3(64), dim3(512), 0, stream,
                       W16, Wih16, biasf, x16, h0b, h1b, ctrb);
    // T=512 even: last write went to buffer 0
    hipLaunchKernelGGL(fc_k, dim3(256), dim3(64), 0, stream, h0b, Wfc, bfc, out);
}